// Round 7
// baseline (244.824 us; speedup 1.0000x reference)
//
#include <hip/hip_runtime.h>

typedef unsigned short u16;
typedef unsigned int u32;
typedef __bf16 bf16;
typedef __bf16 bf16x8 __attribute__((ext_vector_type(8)));
typedef __bf16 bf16x4 __attribute__((ext_vector_type(4)));
typedef float f32x4 __attribute__((ext_vector_type(4)));

#define NSAMP 2048
#define KH 3
#define NNBR 16
#define F 128
#define OUT_O 256   // C_OUT * F_OUT
#define QT 384      // KH * F

// LDS row stride 140 elems = 280 B = 70 banks -> 6-bank rotation per row;
// all 16 'lr' rows hit distinct start banks for b128 reads.
#define ZLD 140
#define YLD 140

__device__ __forceinline__ bf16x4 cvt4(float4 v) {
    bf16x4 h;
    h[0] = (bf16)v.x; h[1] = (bf16)v.y; h[2] = (bf16)v.z; h[3] = (bf16)v.w;
    return h;
}

__global__ void wprep(const float* __restrict__ W, bf16* __restrict__ Wbf) {
    int i = blockIdx.x * 256 + threadIdx.x;
    if (i < OUT_O * QT) Wbf[i] = (bf16)W[i];
}

__launch_bounds__(512, 4)
__global__ void featkhop(const float* __restrict__ xg,
                         const float* __restrict__ ng,
                         const bf16* __restrict__ Wbf,
                         float* __restrict__ out) {
    // Zs rows 0..48 hold x + 48 neighbors (bf16). Rows 49..63 are read by MFMA
    // B-frags as don't-care garbage (their output rows are discarded); the f32
    // scratch arrays are aliased into that tail (2560 B of 4200 B). All writes
    // are barrier-ordered vs those reads, so reads are stable.
    __shared__ __align__(16) bf16 Zs[64 * ZLD];       // 17920 B
    __shared__ __align__(16) bf16 Ys[2][64 * YLD];    // 35840 B, double-buffered
    float* const xls = (float*)(Zs + 49 * ZLD);       // 128 f32
    float* const sls = xls + F;                        // [3][128] f32
    float* const rsi = xls + 4 * F;                    // 128 f32: 1/(colsum+eps), per current q

    const int i = blockIdx.x;
    const int t = threadIdx.x;
    const int lane = t & 63;
    const int w = t >> 6;        // wave 0..7
    const int lr = lane & 15;
    const int lg = lane >> 4;

    // ---- stage x: fp32 to xls, bf16 to Z row 0 ----
    if (t < F / 4) {
        float4 v = *(const float4*)(xg + (size_t)i * F + t * 4);
        *(float4*)(xls + t * 4) = v;
        *(bf16x4*)(Zs + 0 * ZLD + t * 4) = cvt4(v);
    }
    // ---- stage neighbors: bf16 rows 1..48 ----
    {
        const float* nb = ng + (size_t)i * (KH * NNBR * F);
        #pragma unroll
        for (int c = 0; c < 3; ++c) {
            int j = c * 512 + t;
            float4 v = *(const float4*)(nb + j * 4);
            int fl = j * 4;
            int row = 1 + (fl >> 7);     // neighbor 0..47 -> rows 1..48
            int b = fl & 127;
            *(bf16x4*)(Zs + row * ZLD + b) = cvt4(v);
        }
    }
    __syncthreads();                     // bar 1: Zs/xls ready

    // ---- s[q][b] = sum_n nbr[q][n][b] ----
    if (t < KH * F) {
        int q = t >> 7, b = t & 127;
        float s = 0.f;
        #pragma unroll
        for (int n = 0; n < NNBR; ++n) s += (float)Zs[(1 + q * NNBR + n) * ZLD + b];
        sls[q * F + b] = s;
    }
    __syncthreads();                     // bar 2: sls ready

    const int a_row = w * 16 + lr;       // adjacency row this lane owns
    const float x_a = xls[a_row];
    const int cbase = lg * 8;            // within-32 col offset

    f32x4 acc2[4][2];
    {
        f32x4 zf = {0.f, 0.f, 0.f, 0.f};
        #pragma unroll
        for (int mt = 0; mt < 4; ++mt) { acc2[mt][0] = zf; acc2[mt][1] = zf; }
    }

    #pragma unroll
    for (int q = 0; q < KH; ++q) {
        // ---- build u-row ONCE in registers; rowsum (=colsum by symmetry) ----
        // (unrolled: this region co-schedules with GEMM2(q-1)'s MFMAs)
        const float s_a = sls[q * F + a_row];
        float uv[32];
        float ps = 0.f;
        #pragma unroll
        for (int kk = 0; kk < 4; ++kk) {
            float4 xb0 = *(const float4*)(xls + kk * 32 + cbase);
            float4 xb1 = *(const float4*)(xls + kk * 32 + cbase + 4);
            float4 sb0 = *(const float4*)(sls + q * F + kk * 32 + cbase);
            float4 sb1 = *(const float4*)(sls + q * F + kk * 32 + cbase + 4);
            float xb[8] = {xb0.x, xb0.y, xb0.z, xb0.w, xb1.x, xb1.y, xb1.z, xb1.w};
            float sb[8] = {sb0.x, sb0.y, sb0.z, sb0.w, sb1.x, sb1.y, sb1.z, sb1.w};
            #pragma unroll
            for (int e = 0; e < 8; ++e) {
                float tv = x_a * sb[e] + xb[e] * s_a;
                float r = tv * __builtin_amdgcn_rsqf(fmaxf(fabsf(tv), 1e-8f));
                uv[kk * 8 + e] = r;
                ps += fabsf(r);
            }
        }
        ps += __shfl_xor(ps, 16);        // reduce over the 4 lg-mates
        ps += __shfl_xor(ps, 32);
        if (lg == 0) rsi[a_row] = __builtin_amdgcn_rcpf(ps + 1e-7f);
        __syncthreads();                 // bar A(q): rsi complete; Ys[q&1] free

        // ---- GEMM1 (swapped): Y^T = adj * Z^T ; adj frag is the A operand ----
        bf16* Ysb = Ys[q & 1];
        f32x4 acc1[4];
        {
            f32x4 zf = {0.f, 0.f, 0.f, 0.f};
            #pragma unroll
            for (int mt = 0; mt < 4; ++mt) acc1[mt] = zf;
        }
        #pragma unroll
        for (int kk = 0; kk < 4; ++kk) {
            float4 r0 = *(const float4*)(rsi + kk * 32 + cbase);
            float4 r1 = *(const float4*)(rsi + kk * 32 + cbase + 4);
            float rb[8] = {r0.x, r0.y, r0.z, r0.w, r1.x, r1.y, r1.z, r1.w};
            bf16x8 afrag;
            #pragma unroll
            for (int e = 0; e < 8; ++e)
                afrag[e] = (bf16)(uv[kk * 8 + e] * rb[e]);
            #pragma unroll
            for (int mt = 0; mt < 4; ++mt) {
                bf16x8 zfrag = *(const bf16x8*)(Zs + (mt * 16 + lr) * ZLD + kk * 32 + cbase);
                acc1[mt] = __builtin_amdgcn_mfma_f32_16x16x32_bf16(afrag, zfrag, acc1[mt], 0, 0, 0);
            }
        }

        // ---- prefetch W fragments for this q's GEMM2 (issue under GEMM1/Y-store;
        //      the barrier's vmcnt drain guarantees residency after barB) ----
        bf16x8 wf0[4], wf1[4];
        #pragma unroll
        for (int kk = 0; kk < 4; ++kk) {
            const bf16* wp = Wbf + (size_t)(w * 32 + lr) * QT + q * F + kk * 32 + cbase;
            wf0[kk] = *(const bf16x8*)wp;
            wf1[kk] = *(const bf16x8*)(wp + 16 * QT);
        }

        // D: col = lr -> v_local, row = lg*4+r -> a_local => lane holds
        //    Y[v=mt*16+lr][a = w*16+lg*4+r], 4 consecutive a => b64 store.
        #pragma unroll
        for (int mt = 0; mt < 4; ++mt) {
            bf16x4 yv;
            #pragma unroll
            for (int r = 0; r < 4; ++r) yv[r] = (bf16)acc1[mt][r];
            *(bf16x4*)(Ysb + (mt * 16 + lr) * YLD + w * 16 + lg * 4) = yv;
        }
        __syncthreads();                 // bar B(q): Ys[q&1] complete

        // ---- GEMM2 (q-slice): acc2 += Y_q(64x128) @ Wq^T ----
        #pragma unroll
        for (int kk = 0; kk < 4; ++kk) {
            #pragma unroll
            for (int mt = 0; mt < 4; ++mt) {
                bf16x8 af = *(const bf16x8*)(Ysb + (mt * 16 + lr) * YLD + kk * 32 + cbase);
                acc2[mt][0] = __builtin_amdgcn_mfma_f32_16x16x32_bf16(af, wf0[kk], acc2[mt][0], 0, 0, 0);
                acc2[mt][1] = __builtin_amdgcn_mfma_f32_16x16x32_bf16(af, wf1[kk], acc2[mt][1], 0, 0, 0);
            }
        }
        // no trailing barrier: rsi(q+1)/Ys[(q+1)&1] writes are ordered after
        // bar A(q+1), which follows every wave's GEMM2 reads of this q.
    }

    // ---- epilogue: row 0 -> x_out, rows 1..48 -> nbr_out ----
    float* xout = out + (size_t)i * OUT_O;
    float* nout = out + (size_t)NSAMP * OUT_O + (size_t)i * 48 * OUT_O;
    #pragma unroll
    for (int mt = 0; mt < 4; ++mt) {
        #pragma unroll
        for (int r = 0; r < 4; ++r) {
            int v = mt * 16 + lg * 4 + r;
            #pragma unroll
            for (int nn = 0; nn < 2; ++nn) {
                int o = w * 32 + nn * 16 + lr;
                float val = acc2[mt][nn][r];
                if (v == 0) xout[o] = val;
                else if (v <= 48) nout[(size_t)(v - 1) * OUT_O + o] = val;
            }
        }
    }
}

extern "C" void kernel_launch(void* const* d_in, const int* in_sizes, int n_in,
                              void* d_out, int out_size, void* d_ws, size_t ws_size,
                              hipStream_t stream) {
    const float* x   = (const float*)d_in[0];
    const float* nbr = (const float*)d_in[1];
    const float* W   = (const float*)d_in[2];
    bf16* Wbf = (bf16*)d_ws;   // 256*384 bf16 = 192 KiB
    wprep<<<(OUT_O * QT + 255) / 256, 256, 0, stream>>>(W, Wbf);
    featkhop<<<NSAMP, 512, 0, stream>>>(x, nbr, Wbf, (float*)d_out);
}

// Round 8
// 80.549 us; speedup vs baseline: 3.0395x; 3.0395x over previous
//
#include <hip/hip_runtime.h>

typedef unsigned short u16;
typedef unsigned int u32;
typedef __bf16 bf16;
typedef __bf16 bf16x8 __attribute__((ext_vector_type(8)));
typedef __bf16 bf16x4 __attribute__((ext_vector_type(4)));
typedef float f32x4 __attribute__((ext_vector_type(4)));

#define NSAMP 2048
#define KH 3
#define NNBR 16
#define F 128
#define OUT_O 256   // C_OUT * F_OUT
#define QT 384      // KH * F

// LDS row stride MUST be a multiple of 8 elems (16 B) — misaligned b128 LDS
// ops get split by HW (R7: stride 140 = 280 B tripled runtime). 136 = 272 B ok.
#define ZLD 136
#define YLD 136

__device__ __forceinline__ bf16x4 cvt4(float4 v) {
    bf16x4 h;
    h[0] = (bf16)v.x; h[1] = (bf16)v.y; h[2] = (bf16)v.z; h[3] = (bf16)v.w;
    return h;
}

__global__ void wprep(const float* __restrict__ W, bf16* __restrict__ Wbf) {
    int i = blockIdx.x * 256 + threadIdx.x;
    if (i < OUT_O * QT) Wbf[i] = (bf16)W[i];
}

__launch_bounds__(512, 4)
__global__ void featkhop(const float* __restrict__ xg,
                         const float* __restrict__ ng,
                         const bf16* __restrict__ Wbf,
                         float* __restrict__ out) {
    // Zs rows 0..48 hold x + 48 neighbors (bf16). Rows 49..63 are read by MFMA
    // B-frags as don't-care garbage (their output rows are discarded); the f32
    // scratch arrays are aliased into that tail (2560 B of 4080 B). All writes
    // are barrier-ordered vs those reads, so reads are stable.
    __shared__ __align__(16) bf16 Zs[64 * ZLD];       // 17408 B
    __shared__ __align__(16) bf16 Ys[2][64 * YLD];    // 34816 B, double-buffered
    float* const xls = (float*)(Zs + 49 * ZLD);       // 128 f32 (49*136*2 = 13328 B, 16B-aligned)
    float* const sls = xls + F;                        // [3][128] f32
    float* const rsi = xls + 4 * F;                    // 128 f32: 1/(colsum+eps), per current q

    const int i = blockIdx.x;
    const int t = threadIdx.x;
    const int lane = t & 63;
    const int w = t >> 6;        // wave 0..7
    const int lr = lane & 15;
    const int lg = lane >> 4;

    // ---- stage x: fp32 to xls, bf16 to Z row 0 ----
    if (t < F / 4) {
        float4 v = *(const float4*)(xg + (size_t)i * F + t * 4);
        *(float4*)(xls + t * 4) = v;
        *(bf16x4*)(Zs + 0 * ZLD + t * 4) = cvt4(v);
    }
    // ---- stage neighbors: bf16 rows 1..48 ----
    {
        const float* nb = ng + (size_t)i * (KH * NNBR * F);
        #pragma unroll
        for (int c = 0; c < 3; ++c) {
            int j = c * 512 + t;
            float4 v = *(const float4*)(nb + j * 4);
            int fl = j * 4;
            int row = 1 + (fl >> 7);     // neighbor 0..47 -> rows 1..48
            int b = fl & 127;
            *(bf16x4*)(Zs + row * ZLD + b) = cvt4(v);
        }
    }
    __syncthreads();                     // bar 1: Zs/xls ready

    // ---- s[q][b] = sum_n nbr[q][n][b] ----
    if (t < KH * F) {
        int q = t >> 7, b = t & 127;
        float s = 0.f;
        #pragma unroll
        for (int n = 0; n < NNBR; ++n) s += (float)Zs[(1 + q * NNBR + n) * ZLD + b];
        sls[q * F + b] = s;
    }
    __syncthreads();                     // bar 2: sls ready

    const int a_row = w * 16 + lr;       // adjacency row this lane owns
    const float x_a = xls[a_row];
    const int cbase = lg * 8;            // within-32 col offset

    f32x4 acc2[4][2];
    {
        f32x4 zf = {0.f, 0.f, 0.f, 0.f};
        #pragma unroll
        for (int mt = 0; mt < 4; ++mt) { acc2[mt][0] = zf; acc2[mt][1] = zf; }
    }

    #pragma unroll
    for (int q = 0; q < KH; ++q) {
        // ---- build u-row ONCE in registers; rowsum (=colsum by symmetry) ----
        // (unrolled: this region co-schedules with GEMM2(q-1)'s MFMAs)
        const float s_a = sls[q * F + a_row];
        float uv[32];
        float ps = 0.f;
        #pragma unroll
        for (int kk = 0; kk < 4; ++kk) {
            float4 xb0 = *(const float4*)(xls + kk * 32 + cbase);
            float4 xb1 = *(const float4*)(xls + kk * 32 + cbase + 4);
            float4 sb0 = *(const float4*)(sls + q * F + kk * 32 + cbase);
            float4 sb1 = *(const float4*)(sls + q * F + kk * 32 + cbase + 4);
            float xb[8] = {xb0.x, xb0.y, xb0.z, xb0.w, xb1.x, xb1.y, xb1.z, xb1.w};
            float sb[8] = {sb0.x, sb0.y, sb0.z, sb0.w, sb1.x, sb1.y, sb1.z, sb1.w};
            #pragma unroll
            for (int e = 0; e < 8; ++e) {
                float tv = x_a * sb[e] + xb[e] * s_a;
                float r = tv * __builtin_amdgcn_rsqf(fmaxf(fabsf(tv), 1e-8f));
                uv[kk * 8 + e] = r;
                ps += fabsf(r);
            }
        }
        ps += __shfl_xor(ps, 16);        // reduce over the 4 lg-mates
        ps += __shfl_xor(ps, 32);
        if (lg == 0) rsi[a_row] = __builtin_amdgcn_rcpf(ps + 1e-7f);
        __syncthreads();                 // bar A(q): rsi complete; Ys[q&1] free

        // ---- GEMM1 (swapped): Y^T = adj * Z^T ; adj frag is the A operand ----
        bf16* Ysb = Ys[q & 1];
        f32x4 acc1[4];
        {
            f32x4 zf = {0.f, 0.f, 0.f, 0.f};
            #pragma unroll
            for (int mt = 0; mt < 4; ++mt) acc1[mt] = zf;
        }
        #pragma unroll
        for (int kk = 0; kk < 4; ++kk) {
            float4 r0 = *(const float4*)(rsi + kk * 32 + cbase);
            float4 r1 = *(const float4*)(rsi + kk * 32 + cbase + 4);
            float rb[8] = {r0.x, r0.y, r0.z, r0.w, r1.x, r1.y, r1.z, r1.w};
            bf16x8 afrag;
            #pragma unroll
            for (int e = 0; e < 8; ++e)
                afrag[e] = (bf16)(uv[kk * 8 + e] * rb[e]);
            #pragma unroll
            for (int mt = 0; mt < 4; ++mt) {
                bf16x8 zfrag = *(const bf16x8*)(Zs + (mt * 16 + lr) * ZLD + kk * 32 + cbase);
                acc1[mt] = __builtin_amdgcn_mfma_f32_16x16x32_bf16(afrag, zfrag, acc1[mt], 0, 0, 0);
            }
        }

        // ---- prefetch W fragments for this q's GEMM2 (issued under GEMM1's
        //      MFMAs / Y-store; barrier B's vmcnt drain makes them resident) ----
        bf16x8 wf0[4], wf1[4];
        #pragma unroll
        for (int kk = 0; kk < 4; ++kk) {
            const bf16* wp = Wbf + (size_t)(w * 32 + lr) * QT + q * F + kk * 32 + cbase;
            wf0[kk] = *(const bf16x8*)wp;
            wf1[kk] = *(const bf16x8*)(wp + 16 * QT);
        }

        // D: col = lr -> v_local, row = lg*4+r -> a_local => lane holds
        //    Y[v=mt*16+lr][a = w*16+lg*4+r], 4 consecutive a => b64 store.
        #pragma unroll
        for (int mt = 0; mt < 4; ++mt) {
            bf16x4 yv;
            #pragma unroll
            for (int r = 0; r < 4; ++r) yv[r] = (bf16)acc1[mt][r];
            *(bf16x4*)(Ysb + (mt * 16 + lr) * YLD + w * 16 + lg * 4) = yv;
        }
        __syncthreads();                 // bar B(q): Ys[q&1] complete

        // ---- GEMM2 (q-slice): acc2 += Y_q(64x128) @ Wq^T ----
        #pragma unroll
        for (int kk = 0; kk < 4; ++kk) {
            #pragma unroll
            for (int mt = 0; mt < 4; ++mt) {
                bf16x8 af = *(const bf16x8*)(Ysb + (mt * 16 + lr) * YLD + kk * 32 + cbase);
                acc2[mt][0] = __builtin_amdgcn_mfma_f32_16x16x32_bf16(af, wf0[kk], acc2[mt][0], 0, 0, 0);
                acc2[mt][1] = __builtin_amdgcn_mfma_f32_16x16x32_bf16(af, wf1[kk], acc2[mt][1], 0, 0, 0);
            }
        }
        // no trailing barrier: rsi(q+1)/Ys[(q+1)&1] writes are ordered after
        // bar A(q+1), which follows every wave's GEMM2 reads of this q.
    }

    // ---- epilogue: row 0 -> x_out, rows 1..48 -> nbr_out ----
    float* xout = out + (size_t)i * OUT_O;
    float* nout = out + (size_t)NSAMP * OUT_O + (size_t)i * 48 * OUT_O;
    #pragma unroll
    for (int mt = 0; mt < 4; ++mt) {
        #pragma unroll
        for (int r = 0; r < 4; ++r) {
            int v = mt * 16 + lg * 4 + r;
            #pragma unroll
            for (int nn = 0; nn < 2; ++nn) {
                int o = w * 32 + nn * 16 + lr;
                float val = acc2[mt][nn][r];
                if (v == 0) xout[o] = val;
                else if (v <= 48) nout[(size_t)(v - 1) * OUT_O + o] = val;
            }
        }
    }
}

extern "C" void kernel_launch(void* const* d_in, const int* in_sizes, int n_in,
                              void* d_out, int out_size, void* d_ws, size_t ws_size,
                              hipStream_t stream) {
    const float* x   = (const float*)d_in[0];
    const float* nbr = (const float*)d_in[1];
    const float* W   = (const float*)d_in[2];
    bf16* Wbf = (bf16*)d_ws;   // 256*384 bf16 = 192 KiB
    wprep<<<(OUT_O * QT + 255) / 256, 256, 0, stream>>>(W, Wbf);
    featkhop<<<NSAMP, 512, 0, stream>>>(x, nbr, Wbf, (float*)d_out);
}